// Round 4
// baseline (1497.488 us; speedup 1.0000x reference)
//
#include <hip/hip_runtime.h>
#include <hip/hip_bf16.h>
#include <stdint.h>

// WindowAttention (B=64, N=1024=32x32 tokens, DIM=256, H=8, Dh=64, INNER=512)
// Batch-chunked pipeline (CB batches per chunk, chosen from ws_size; max 16):
//   P0: w_qkv -> [1536][256] bf16^T; w_pro -> [1536][1536] bf16^T   (once)
//   per chunk:
//     conv: x -> bf16
//     G1 (MFMA bf16): gelu(x @ w_qkv) -> bf16        [CM x 1536]
//     G2 (MFMA bf16): g1 @ w_pro + b_pro -> fp32     [CM x 1536]
//     AT: window attention (fp32), strides 0/4, padded-softmax semantics
//     G4 (fp32 VALU): 0.5*(att0+att4) @ w_out + b_out -> d_out chunk
// Round-3 crash fixes: (1) workspace need now <= 232 MB and adapts to ws_size
// via batch chunking; (2) __align__(16) on all LDS arrays read as b128.

#define TILE 64
#define BKK  32

typedef short bf16x8 __attribute__((ext_vector_type(8)));
typedef float f32x4 __attribute__((ext_vector_type(4)));

__device__ __forceinline__ unsigned short f2bf(float f) {
    unsigned u = __float_as_uint(f);
    return (unsigned short)((u + 0x7fffu + ((u >> 16) & 1u)) >> 16);
}

__device__ __forceinline__ float gelu_exact(float v) {
    return 0.5f * v * (1.0f + erff(v * 0.70710678118654752f));
}

// ---------------- fp32 -> bf16 elementwise ----------------
__global__ __launch_bounds__(256) void conv_bf16(const float* __restrict__ src,
                                                 unsigned short* __restrict__ dst, int n4) {
    int i = blockIdx.x * 256 + threadIdx.x;
    const int stride = gridDim.x * 256;
    for (; i < n4; i += stride) {
        float4 v = reinterpret_cast<const float4*>(src)[i];
        ushort4 o;
        o.x = f2bf(v.x); o.y = f2bf(v.y); o.z = f2bf(v.z); o.w = f2bf(v.w);
        reinterpret_cast<ushort4*>(dst)[i] = o;
    }
}

// ---------------- w [K][N] fp32 -> wT [N][K] bf16 ----------------
__global__ __launch_bounds__(256) void transpose_bf16(const float* __restrict__ w,
                                                      unsigned short* __restrict__ wT,
                                                      int K, int N) {
    __shared__ float t[32][33];
    const int kb = blockIdx.y * 32, nb = blockIdx.x * 32;
    const int r = threadIdx.x >> 5, c = threadIdx.x & 31;
    #pragma unroll
    for (int i = 0; i < 4; ++i)
        t[r + i * 8][c] = w[(size_t)(kb + r + i * 8) * N + nb + c];
    __syncthreads();
    #pragma unroll
    for (int i = 0; i < 4; ++i)
        wT[(size_t)(nb + r + i * 8) * K + kb + c] = f2bf(t[c][r + i * 8]);
}

// ---------------- MFMA bf16 GEMM: C = A[M][K] @ BT[N][K]^T ----------------
template<bool GELU, bool BIAS, bool OUTBF>
__global__ __launch_bounds__(256) void gemm_mfma(
    const unsigned short* __restrict__ A,   // [M][K] bf16
    const unsigned short* __restrict__ BT,  // [N][K] bf16
    const float* __restrict__ bias,
    void* __restrict__ Cv, int M, int N, int K, int nbx)
{
    __shared__ __align__(16) short lA[128 * BKK];  // [m][k] linear (8 KB)
    __shared__ __align__(16) short lB[128 * BKK];  // [n][k] linear (8 KB)
    const int tid  = threadIdx.x;
    const int lane = tid & 63;
    const int wid  = tid >> 6;

    // XCD-aware swizzle (gridDim.x % 8 == 0): each XCD gets a contiguous chunk.
    const int cpx = gridDim.x >> 3;
    const int wg  = (blockIdx.x & 7) * cpx + (blockIdx.x >> 3);
    const int nb  = wg % nbx, mb = wg / nbx;

    const size_t bm = (size_t)mb * 128;
    const size_t bn = (size_t)nb * 128;

    const int wr = wid >> 1, wc = wid & 1;   // 2x2 wave grid, 64x64 out per wave
    const int mr = wr * 64, nr = wc * 64;

    f32x4 acc[4][4] = {};

    // staging: instr i = wid*2+s covers tile rows [16i,16i+16); lane l ->
    // row 16i + l/4, k-chunk (l&3)*8 shorts. LDS dest = uniform base + lane*16B.
    const int srow = lane >> 2;
    const int sk8  = lane & 3;

    for (int k0 = 0; k0 < K; k0 += BKK) {
        #pragma unroll
        for (int s = 0; s < 2; ++s) {
            const int i = wid * 2 + s;
            const int row = i * 16 + srow;
            const unsigned short* ga = A  + (bm + row) * (size_t)K + k0 + sk8 * 8;
            const unsigned short* gb = BT + (bn + row) * (size_t)K + k0 + sk8 * 8;
            __builtin_amdgcn_global_load_lds(
                (const __attribute__((address_space(1))) unsigned int*)ga,
                (__attribute__((address_space(3))) unsigned int*)(lA + i * 512), 16, 0, 0);
            __builtin_amdgcn_global_load_lds(
                (const __attribute__((address_space(1))) unsigned int*)gb,
                (__attribute__((address_space(3))) unsigned int*)(lB + i * 512), 16, 0, 0);
        }
        __syncthreads();   // compiler emits vmcnt(0) drain before barrier

        const int fr = lane & 15;
        const int fk = (lane >> 4) * 8;
        bf16x8 af[4], bq[4];
        #pragma unroll
        for (int m = 0; m < 4; ++m)
            af[m] = *reinterpret_cast<const bf16x8*>(&lA[(mr + m * 16 + fr) * BKK + fk]);
        #pragma unroll
        for (int n = 0; n < 4; ++n)
            bq[n] = *reinterpret_cast<const bf16x8*>(&lB[(nr + n * 16 + fr) * BKK + fk]);
        #pragma unroll
        for (int m = 0; m < 4; ++m)
            #pragma unroll
            for (int n = 0; n < 4; ++n)
                acc[m][n] = __builtin_amdgcn_mfma_f32_16x16x32_bf16(af[m], bq[n], acc[m][n], 0, 0, 0);
        __syncthreads();
    }

    // epilogue: D frag = col lane&15, row (lane>>4)*4 + j  [verified m89/m91]
    const int fr = lane & 15;
    const int fq = lane >> 4;
    #pragma unroll
    for (int n = 0; n < 4; ++n) {
        const size_t col = bn + nr + n * 16 + fr;
        const float bv = BIAS ? bias[col] : 0.0f;
        #pragma unroll
        for (int m = 0; m < 4; ++m) {
            const size_t rbase = bm + mr + m * 16 + fq * 4;
            f32x4 a = acc[m][n];
            #pragma unroll
            for (int j = 0; j < 4; ++j) {
                float v = a[j] + bv;
                if (GELU) v = gelu_exact(v);
                if (OUTBF)
                    ((unsigned short*)Cv)[(rbase + j) * (size_t)N + col] = f2bf(v);
                else
                    ((float*)Cv)[(rbase + j) * (size_t)N + col] = v;
            }
        }
    }
}

// ---------------- fp32 VALU GEMM (G4 only) ----------------
template<bool GELU, bool BIAS, bool MEANA>
__global__ __launch_bounds__(256) void gemm_f32(
    const float* __restrict__ A, const float* __restrict__ A2,
    const float* __restrict__ B, const float* __restrict__ bias,
    float* __restrict__ C, int M, int N, int K)
{
    __shared__ __align__(16) float As[BKK][TILE + 4];
    __shared__ __align__(16) float Bs[BKK][TILE + 4];
    const int tid = threadIdx.x;
    const int tx = tid & 15;
    const int ty = tid >> 4;
    const long bm = (long)blockIdx.y * TILE;
    const long bn = (long)blockIdx.x * TILE;

    float acc[4][4] = {};

    for (int k0 = 0; k0 < K; k0 += BKK) {
        #pragma unroll
        for (int i = 0; i < 2; ++i) {
            int f4  = tid + i * 256;
            int row = f4 >> 3;
            int kk  = (f4 & 7) << 2;
            float4 a = *reinterpret_cast<const float4*>(A + (bm + row) * (long)K + k0 + kk);
            if (MEANA) {
                float4 a2 = *reinterpret_cast<const float4*>(A2 + (bm + row) * (long)K + k0 + kk);
                a.x = 0.5f * (a.x + a2.x); a.y = 0.5f * (a.y + a2.y);
                a.z = 0.5f * (a.z + a2.z); a.w = 0.5f * (a.w + a2.w);
            }
            As[kk + 0][row] = a.x; As[kk + 1][row] = a.y;
            As[kk + 2][row] = a.z; As[kk + 3][row] = a.w;
        }
        #pragma unroll
        for (int i = 0; i < 2; ++i) {
            int f4   = tid + i * 256;
            int krow = f4 >> 4;
            int nn   = (f4 & 15) << 2;
            *reinterpret_cast<float4*>(&Bs[krow][nn]) =
                *reinterpret_cast<const float4*>(B + (long)(k0 + krow) * N + bn + nn);
        }
        __syncthreads();
        #pragma unroll
        for (int kk = 0; kk < BKK; ++kk) {
            float4 av = *reinterpret_cast<const float4*>(&As[kk][ty << 2]);
            float4 bv = *reinterpret_cast<const float4*>(&Bs[kk][tx << 2]);
            float a_[4] = {av.x, av.y, av.z, av.w};
            float b_[4] = {bv.x, bv.y, bv.z, bv.w};
            #pragma unroll
            for (int u = 0; u < 4; ++u)
                #pragma unroll
                for (int w = 0; w < 4; ++w)
                    acc[u][w] = fmaf(a_[u], b_[w], acc[u][w]);
        }
        __syncthreads();
    }

    #pragma unroll
    for (int u = 0; u < 4; ++u) {
        long row = bm + (ty << 2) + u;
        float vals[4];
        #pragma unroll
        for (int w = 0; w < 4; ++w) {
            float v = acc[u][w];
            if (BIAS) v += bias[bn + (tx << 2) + w];
            if (GELU) v = gelu_exact(v);
            vals[w] = v;
        }
        *reinterpret_cast<float4*>(C + row * (long)N + bn + (tx << 2)) =
            make_float4(vals[0], vals[1], vals[2], vals[3]);
    }
}

// ---------------- window attention (fp32) ----------------
// One block per (window, head, batch-in-chunk). widx 0..15 -> stride 0,
// widx 16..40 -> stride 4 (5x5 grid; edge windows 4 wide).
__global__ __launch_bounds__(256) void attn_win(
    const float* __restrict__ qkvp, float* __restrict__ out0, float* __restrict__ out4)
{
    __shared__ __align__(16) float qT[64][68];
    __shared__ __align__(16) float kT[64][68];
    __shared__ __align__(16) float vS[64][68];
    __shared__ float pS[64][66];
    __shared__ float invS[64];

    const int widx = blockIdx.x;
    const int h    = blockIdx.y;
    const int b    = blockIdx.z;
    const int tid  = threadIdx.x;

    int r0, c0, nr, nc;
    float* outbuf;
    if (widx < 16) {
        r0 = (widx >> 2) << 3; c0 = (widx & 3) << 3;
        nr = 8; nc = 8;
        outbuf = out0;
    } else {
        int w  = widx - 16;
        int ri = w / 5, ci = w % 5;
        r0 = (ri == 0) ? 0 : (8 * ri - 4);           // starts {0,4,12,20,28}
        nr = (ri == 0 || ri == 4) ? 4 : 8;
        c0 = (ci == 0) ? 0 : (8 * ci - 4);
        nc = (ci == 0 || ci == 4) ? 4 : 8;
        outbuf = out4;
    }
    const int num = nr * nc;                          // 16, 32, or 64
    const int ncl = (nc == 8) ? 3 : 2;
    const size_t tokbase = (size_t)b * 1024;

    for (int f4 = tid; f4 < num * 16; f4 += 256) {
        int t  = f4 >> 4;
        int d4 = (f4 & 15) << 2;
        int n  = ((r0 + (t >> ncl)) << 5) + c0 + (t & (nc - 1));
        const float* base = qkvp + (tokbase + n) * 1536 + h * 64 + d4;
        float4 qv = *reinterpret_cast<const float4*>(base);
        float4 kv = *reinterpret_cast<const float4*>(base + 512);
        float4 vv = *reinterpret_cast<const float4*>(base + 1024);
        qT[d4 + 0][t] = qv.x; qT[d4 + 1][t] = qv.y; qT[d4 + 2][t] = qv.z; qT[d4 + 3][t] = qv.w;
        kT[d4 + 0][t] = kv.x; kT[d4 + 1][t] = kv.y; kT[d4 + 2][t] = kv.z; kT[d4 + 3][t] = kv.w;
        *reinterpret_cast<float4*>(&vS[t][d4]) = vv;
    }
    __syncthreads();

    const int i0 = (tid >> 4) << 2;
    const int j0 = (tid & 15) << 2;
    if (i0 < num && j0 < num) {
        float acc[4][4] = {};
        #pragma unroll 16
        for (int d = 0; d < 64; ++d) {
            float4 qv = *reinterpret_cast<const float4*>(&qT[d][i0]);
            float4 kv = *reinterpret_cast<const float4*>(&kT[d][j0]);
            float q_[4] = {qv.x, qv.y, qv.z, qv.w};
            float k_[4] = {kv.x, kv.y, kv.z, kv.w};
            #pragma unroll
            for (int u = 0; u < 4; ++u)
                #pragma unroll
                for (int w = 0; w < 4; ++w)
                    acc[u][w] = fmaf(q_[u], k_[w], acc[u][w]);
        }
        #pragma unroll
        for (int u = 0; u < 4; ++u)
            #pragma unroll
            for (int w = 0; w < 4; ++w)
                pS[i0 + u][j0 + w] = acc[u][w] * 0.125f;
    }
    __syncthreads();

    // padded softmax: pad keys have logit exactly 0 and ARE included (ref
    // softmaxes over zero-padded keys): max includes 0, denom += (64-num)e^-m.
    if (tid < num) {
        const int i = tid;
        float m = (num < 64) ? 0.0f : -3.4e38f;
        for (int j = 0; j < num; ++j) m = fmaxf(m, pS[i][j]);
        float s = (float)(64 - num) * __expf(-m);
        for (int j = 0; j < num; ++j) {
            float e = __expf(pS[i][j] - m);
            pS[i][j] = e;
            s += e;
        }
        invS[i] = 1.0f / s;
    }
    __syncthreads();

    const int d0 = j0;
    if (i0 < num) {
        float acc[4][4] = {};
        #pragma unroll 8
        for (int j = 0; j < num; ++j) {
            float4 vv = *reinterpret_cast<const float4*>(&vS[j][d0]);
            float v_[4] = {vv.x, vv.y, vv.z, vv.w};
            float p_[4];
            #pragma unroll
            for (int u = 0; u < 4; ++u) p_[u] = pS[i0 + u][j];
            #pragma unroll
            for (int u = 0; u < 4; ++u)
                #pragma unroll
                for (int w = 0; w < 4; ++w)
                    acc[u][w] = fmaf(p_[u], v_[w], acc[u][w]);
        }
        #pragma unroll
        for (int u = 0; u < 4; ++u) {
            int t = i0 + u;
            int n = ((r0 + (t >> ncl)) << 5) + c0 + (t & (nc - 1));
            float inv = invS[t];
            *reinterpret_cast<float4*>(outbuf + (tokbase + n) * 512 + h * 64 + d0) =
                make_float4(acc[u][0] * inv, acc[u][1] * inv, acc[u][2] * inv, acc[u][3] * inv);
        }
    }
}

extern "C" void kernel_launch(void* const* d_in, const int* in_sizes, int n_in,
                              void* d_out, int out_size, void* d_ws, size_t ws_size,
                              hipStream_t stream) {
    const float* x     = (const float*)d_in[0];  // [64,1024,256]
    const float* w_qkv = (const float*)d_in[1];  // [256,1536]
    const float* w_pro = (const float*)d_in[2];  // [1536,1536]
    const float* b_pro = (const float*)d_in[3];  // [1536]
    const float* w_out = (const float*)d_in[4];  // [512,256]
    const float* b_out = (const float*)d_in[5];  // [256]
    float* out = (float*)d_out;                  // [64,1024,256]

    const int B = 64;
    // per-chunk bytes (CB batches, CM = CB*1024 tokens):
    //   xb  CB*0.5MB | gelu CB*3MB | qkvp CB*6MB | att0/att4 CB*2MB each
    const size_t WQKVT = 1536 * 256 * 2;             // 786,432
    const size_t WPROT = 1536 * 1536 * 2;            // 4,718,592
    const size_t PERB  = 1024 * (256 * 2 + 1536 * 2 + 1536 * 4 + 512 * 4 + 512 * 4);
    int CB = 16;                                     // cap: chunk fits in L3
    while (CB > 1 && WQKVT + WPROT + (size_t)CB * PERB > ws_size) CB >>= 1;
    const int NCHUNK = B / CB;
    const int CM = CB * 1024;

    char* w8 = (char*)d_ws;
    unsigned short* wqkvT = (unsigned short*)w8;                    // [1536][256]
    unsigned short* wproT = (unsigned short*)(w8 + WQKVT);          // [1536][1536]
    char* cbase = w8 + WQKVT + WPROT;
    unsigned short* xb     = (unsigned short*)cbase;                          // CM*256 bf16
    unsigned short* gelu_b = (unsigned short*)(cbase + (size_t)CM * 512);     // CM*1536 bf16
    float*          qkvp   = (float*)(cbase + (size_t)CM * 512 + (size_t)CM * 3072);
    float*          att0   = (float*)((char*)qkvp + (size_t)CM * 6144);       // CM*512 f32
    float*          att4   = (float*)((char*)att0 + (size_t)CM * 2048);       // CM*512 f32

    dim3 blk(256);

    // weight prep (once per launch)
    transpose_bf16<<<dim3(1536 / 32, 256 / 32), blk, 0, stream>>>(w_qkv, wqkvT, 256, 1536);
    transpose_bf16<<<dim3(1536 / 32, 1536 / 32), blk, 0, stream>>>(w_pro, wproT, 1536, 1536);

    const int nbx = 12;                              // 1536/128
    const int gg  = (CM / 128) * nbx;                // G1/G2 grid; CM pow2 -> %8==0

    for (int c = 0; c < NCHUNK; ++c) {
        const size_t tok0 = (size_t)c * CM;
        conv_bf16<<<512, blk, 0, stream>>>(x + tok0 * 256, xb, CM * 256 / 4);
        gemm_mfma<true, false, true><<<gg, blk, 0, stream>>>(
            xb, wqkvT, nullptr, gelu_b, CM, 1536, 256, nbx);
        gemm_mfma<false, true, false><<<gg, blk, 0, stream>>>(
            gelu_b, wproT, b_pro, qkvp, CM, 1536, 1536, nbx);
        attn_win<<<dim3(41, 8, CB), blk, 0, stream>>>(qkvp, att0, att4);
        gemm_f32<false, true, true><<<dim3(256 / TILE, CM / TILE), blk, 0, stream>>>(
            att0, att4, w_out, b_out, out + tok0 * 256, CM, 256, 512);
    }
}

// Round 5
// 1329.828 us; speedup vs baseline: 1.1261x; 1.1261x over previous
//
#include <hip/hip_runtime.h>
#include <hip/hip_bf16.h>
#include <stdint.h>

// WindowAttention (B=64, N=1024=32x32 tokens, DIM=256, H=8, Dh=64, INNER=512)
// Batch-chunked pipeline (CB batches per chunk from ws_size; cap 16 = L3-resident):
//   P0 (once): w_qkv -> [1536][256] bf16^T; w_pro -> [1536][1536] bf16^T;
//              w4T[256][1024] = stack(0.5*w_out^T, 0.5*w_out^T) bf16
//   per chunk:
//     conv: x -> bf16
//     G1 (MFMA): gelu(x @ w_qkv) -> bf16             [CM x 1536]
//     G2 (MFMA): g1 @ w_pro + b_pro -> bf16          [CM x 1536]
//     AT: window attention (fp32 compute, bf16 io) -> attc[CM][1024]
//         (cols 0..511 = stride-0 out, 512..1023 = stride-4 out)
//     G4 (MFMA): attc @ w4T + b_out -> fp32 d_out    (mean folded into w4T)
// R4 -> R5: G4 fp32-VALU -> MFMA via concat-mean trick; G2 outputs bf16.

#define BKK 32

typedef short bf16x8 __attribute__((ext_vector_type(8)));
typedef float f32x4 __attribute__((ext_vector_type(4)));

__device__ __forceinline__ unsigned short f2bf(float f) {
    unsigned u = __float_as_uint(f);
    return (unsigned short)((u + 0x7fffu + ((u >> 16) & 1u)) >> 16);
}
__device__ __forceinline__ float bf2f(unsigned short u) {
    return __uint_as_float((unsigned)u << 16);
}
__device__ __forceinline__ float gelu_exact(float v) {
    return 0.5f * v * (1.0f + erff(v * 0.70710678118654752f));
}

// ---------------- fp32 -> bf16 elementwise ----------------
__global__ __launch_bounds__(256) void conv_bf16(const float* __restrict__ src,
                                                 unsigned short* __restrict__ dst, int n4) {
    int i = blockIdx.x * 256 + threadIdx.x;
    const int stride = gridDim.x * 256;
    for (; i < n4; i += stride) {
        float4 v = reinterpret_cast<const float4*>(src)[i];
        ushort4 o;
        o.x = f2bf(v.x); o.y = f2bf(v.y); o.z = f2bf(v.z); o.w = f2bf(v.w);
        reinterpret_cast<ushort4*>(dst)[i] = o;
    }
}

// ---------------- w [K][N] fp32 -> wT [N][K] bf16 ----------------
__global__ __launch_bounds__(256) void transpose_bf16(const float* __restrict__ w,
                                                      unsigned short* __restrict__ wT,
                                                      int K, int N) {
    __shared__ float t[32][33];
    const int kb = blockIdx.y * 32, nb = blockIdx.x * 32;
    const int r = threadIdx.x >> 5, c = threadIdx.x & 31;
    #pragma unroll
    for (int i = 0; i < 4; ++i)
        t[r + i * 8][c] = w[(size_t)(kb + r + i * 8) * N + nb + c];
    __syncthreads();
    #pragma unroll
    for (int i = 0; i < 4; ++i)
        wT[(size_t)(nb + r + i * 8) * K + kb + c] = f2bf(t[c][r + i * 8]);
}

// ---------------- w_out [512][256] -> w4T [256][1024] = [0.5W^T | 0.5W^T] ----------------
__global__ __launch_bounds__(256) void make_w4T(const float* __restrict__ w,
                                                unsigned short* __restrict__ w4T) {
    __shared__ float t[32][33];
    const int kb = blockIdx.y * 32, nb = blockIdx.x * 32;   // k in [0,512), n in [0,256)
    const int r = threadIdx.x >> 5, c = threadIdx.x & 31;
    #pragma unroll
    for (int i = 0; i < 4; ++i)
        t[r + i * 8][c] = w[(size_t)(kb + r + i * 8) * 256 + nb + c];
    __syncthreads();
    #pragma unroll
    for (int i = 0; i < 4; ++i) {
        unsigned short v = f2bf(0.5f * t[c][r + i * 8]);
        size_t n = nb + r + i * 8, k = kb + c;
        w4T[n * 1024 + k]       = v;
        w4T[n * 1024 + 512 + k] = v;
    }
}

// ---------------- MFMA bf16 GEMM: C = A[M][K] @ BT[N][K]^T ----------------
template<bool GELU, bool BIAS, bool OUTBF>
__global__ __launch_bounds__(256) void gemm_mfma(
    const unsigned short* __restrict__ A,   // [M][K] bf16
    const unsigned short* __restrict__ BT,  // [N][K] bf16
    const float* __restrict__ bias,
    void* __restrict__ Cv, int M, int N, int K, int nbx)
{
    __shared__ __align__(16) short lA[128 * BKK];  // [m][k] linear (8 KB)
    __shared__ __align__(16) short lB[128 * BKK];  // [n][k] linear (8 KB)
    const int tid  = threadIdx.x;
    const int lane = tid & 63;
    const int wid  = tid >> 6;

    // XCD-aware swizzle (gridDim.x % 8 == 0): each XCD gets a contiguous chunk.
    const int cpx = gridDim.x >> 3;
    const int wg  = (blockIdx.x & 7) * cpx + (blockIdx.x >> 3);
    const int nb  = wg % nbx, mb = wg / nbx;

    const size_t bm = (size_t)mb * 128;
    const size_t bn = (size_t)nb * 128;

    const int wr = wid >> 1, wc = wid & 1;   // 2x2 wave grid, 64x64 out per wave
    const int mr = wr * 64, nr = wc * 64;

    f32x4 acc[4][4] = {};

    // staging: instr i = wid*2+s covers tile rows [16i,16i+16); lane l ->
    // row 16i + l/4, k-chunk (l&3)*8 shorts. LDS dest = uniform base + lane*16B.
    const int srow = lane >> 2;
    const int sk8  = lane & 3;

    for (int k0 = 0; k0 < K; k0 += BKK) {
        #pragma unroll
        for (int s = 0; s < 2; ++s) {
            const int i = wid * 2 + s;
            const int row = i * 16 + srow;
            const unsigned short* ga = A  + (bm + row) * (size_t)K + k0 + sk8 * 8;
            const unsigned short* gb = BT + (bn + row) * (size_t)K + k0 + sk8 * 8;
            __builtin_amdgcn_global_load_lds(
                (const __attribute__((address_space(1))) unsigned int*)ga,
                (__attribute__((address_space(3))) unsigned int*)(lA + i * 512), 16, 0, 0);
            __builtin_amdgcn_global_load_lds(
                (const __attribute__((address_space(1))) unsigned int*)gb,
                (__attribute__((address_space(3))) unsigned int*)(lB + i * 512), 16, 0, 0);
        }
        __syncthreads();

        const int fr = lane & 15;
        const int fk = (lane >> 4) * 8;
        bf16x8 af[4], bq[4];
        #pragma unroll
        for (int m = 0; m < 4; ++m)
            af[m] = *reinterpret_cast<const bf16x8*>(&lA[(mr + m * 16 + fr) * BKK + fk]);
        #pragma unroll
        for (int n = 0; n < 4; ++n)
            bq[n] = *reinterpret_cast<const bf16x8*>(&lB[(nr + n * 16 + fr) * BKK + fk]);
        #pragma unroll
        for (int m = 0; m < 4; ++m)
            #pragma unroll
            for (int n = 0; n < 4; ++n)
                acc[m][n] = __builtin_amdgcn_mfma_f32_16x16x32_bf16(af[m], bq[n], acc[m][n], 0, 0, 0);
        __syncthreads();
    }

    // epilogue: D frag = col lane&15, row (lane>>4)*4 + j  [verified m89/m91]
    const int fr = lane & 15;
    const int fq = lane >> 4;
    #pragma unroll
    for (int n = 0; n < 4; ++n) {
        const size_t col = bn + nr + n * 16 + fr;
        const float bv = BIAS ? bias[col] : 0.0f;
        #pragma unroll
        for (int m = 0; m < 4; ++m) {
            const size_t rbase = bm + mr + m * 16 + fq * 4;
            f32x4 a = acc[m][n];
            #pragma unroll
            for (int j = 0; j < 4; ++j) {
                float v = a[j] + bv;
                if (GELU) v = gelu_exact(v);
                if (OUTBF)
                    ((unsigned short*)Cv)[(rbase + j) * (size_t)N + col] = f2bf(v);
                else
                    ((float*)Cv)[(rbase + j) * (size_t)N + col] = v;
            }
        }
    }
}

// ---------------- window attention (fp32 compute, bf16 in/out) ----------------
// One block per (window, head, batch-in-chunk). widx 0..15 -> stride 0,
// widx 16..40 -> stride 4 (5x5 grid; edge windows 4 wide).
// Writes bf16 into attc[token][1024]: cols 0..511 = s0, 512..1023 = s4.
__global__ __launch_bounds__(256) void attn_win(
    const unsigned short* __restrict__ qkvp, unsigned short* __restrict__ attc)
{
    __shared__ __align__(16) float qT[64][68];
    __shared__ __align__(16) float kT[64][68];
    __shared__ __align__(16) float vS[64][68];
    __shared__ float pS[64][66];
    __shared__ float invS[64];

    const int widx = blockIdx.x;
    const int h    = blockIdx.y;
    const int b    = blockIdx.z;
    const int tid  = threadIdx.x;

    int r0, c0, nr, nc, sOff;
    if (widx < 16) {
        r0 = (widx >> 2) << 3; c0 = (widx & 3) << 3;
        nr = 8; nc = 8; sOff = 0;
    } else {
        int w  = widx - 16;
        int ri = w / 5, ci = w % 5;
        r0 = (ri == 0) ? 0 : (8 * ri - 4);           // starts {0,4,12,20,28}
        nr = (ri == 0 || ri == 4) ? 4 : 8;
        c0 = (ci == 0) ? 0 : (8 * ci - 4);
        nc = (ci == 0 || ci == 4) ? 4 : 8;
        sOff = 512;
    }
    const int num = nr * nc;                          // 16, 32, or 64
    const int ncl = (nc == 8) ? 3 : 2;
    const size_t tokbase = (size_t)b * 1024;

    for (int f4 = tid; f4 < num * 16; f4 += 256) {
        int t  = f4 >> 4;
        int d4 = (f4 & 15) << 2;
        int n  = ((r0 + (t >> ncl)) << 5) + c0 + (t & (nc - 1));
        const unsigned short* base = qkvp + (tokbase + n) * 1536 + h * 64 + d4;
        ushort4 qv = *reinterpret_cast<const ushort4*>(base);
        ushort4 kv = *reinterpret_cast<const ushort4*>(base + 512);
        ushort4 vv = *reinterpret_cast<const ushort4*>(base + 1024);
        qT[d4 + 0][t] = bf2f(qv.x); qT[d4 + 1][t] = bf2f(qv.y);
        qT[d4 + 2][t] = bf2f(qv.z); qT[d4 + 3][t] = bf2f(qv.w);
        kT[d4 + 0][t] = bf2f(kv.x); kT[d4 + 1][t] = bf2f(kv.y);
        kT[d4 + 2][t] = bf2f(kv.z); kT[d4 + 3][t] = bf2f(kv.w);
        vS[t][d4 + 0] = bf2f(vv.x); vS[t][d4 + 1] = bf2f(vv.y);
        vS[t][d4 + 2] = bf2f(vv.z); vS[t][d4 + 3] = bf2f(vv.w);
    }
    __syncthreads();

    const int i0 = (tid >> 4) << 2;
    const int j0 = (tid & 15) << 2;
    if (i0 < num && j0 < num) {
        float acc[4][4] = {};
        #pragma unroll 16
        for (int d = 0; d < 64; ++d) {
            float4 qv = *reinterpret_cast<const float4*>(&qT[d][i0]);
            float4 kv = *reinterpret_cast<const float4*>(&kT[d][j0]);
            float q_[4] = {qv.x, qv.y, qv.z, qv.w};
            float k_[4] = {kv.x, kv.y, kv.z, kv.w};
            #pragma unroll
            for (int u = 0; u < 4; ++u)
                #pragma unroll
                for (int w = 0; w < 4; ++w)
                    acc[u][w] = fmaf(q_[u], k_[w], acc[u][w]);
        }
        #pragma unroll
        for (int u = 0; u < 4; ++u)
            #pragma unroll
            for (int w = 0; w < 4; ++w)
                pS[i0 + u][j0 + w] = acc[u][w] * 0.125f;
    }
    __syncthreads();

    // padded softmax: pad keys have logit exactly 0 and ARE included (ref
    // softmaxes over zero-padded keys): max includes 0, denom += (64-num)e^-m.
    if (tid < num) {
        const int i = tid;
        float m = (num < 64) ? 0.0f : -3.4e38f;
        for (int j = 0; j < num; ++j) m = fmaxf(m, pS[i][j]);
        float s = (float)(64 - num) * __expf(-m);
        for (int j = 0; j < num; ++j) {
            float e = __expf(pS[i][j] - m);
            pS[i][j] = e;
            s += e;
        }
        invS[i] = 1.0f / s;
    }
    __syncthreads();

    const int d0 = j0;
    if (i0 < num) {
        float acc[4][4] = {};
        #pragma unroll 8
        for (int j = 0; j < num; ++j) {
            float4 vv = *reinterpret_cast<const float4*>(&vS[j][d0]);
            float v_[4] = {vv.x, vv.y, vv.z, vv.w};
            float p_[4];
            #pragma unroll
            for (int u = 0; u < 4; ++u) p_[u] = pS[i0 + u][j];
            #pragma unroll
            for (int u = 0; u < 4; ++u)
                #pragma unroll
                for (int w = 0; w < 4; ++w)
                    acc[u][w] = fmaf(p_[u], v_[w], acc[u][w]);
        }
        #pragma unroll
        for (int u = 0; u < 4; ++u) {
            int t = i0 + u;
            int n = ((r0 + (t >> ncl)) << 5) + c0 + (t & (nc - 1));
            float inv = invS[t];
            ushort4 o;
            o.x = f2bf(acc[u][0] * inv); o.y = f2bf(acc[u][1] * inv);
            o.z = f2bf(acc[u][2] * inv); o.w = f2bf(acc[u][3] * inv);
            *reinterpret_cast<ushort4*>(attc + (tokbase + n) * 1024 + sOff + h * 64 + d0) = o;
        }
    }
}

extern "C" void kernel_launch(void* const* d_in, const int* in_sizes, int n_in,
                              void* d_out, int out_size, void* d_ws, size_t ws_size,
                              hipStream_t stream) {
    const float* x     = (const float*)d_in[0];  // [64,1024,256]
    const float* w_qkv = (const float*)d_in[1];  // [256,1536]
    const float* w_pro = (const float*)d_in[2];  // [1536,1536]
    const float* b_pro = (const float*)d_in[3];  // [1536]
    const float* w_out = (const float*)d_in[4];  // [512,256]
    const float* b_out = (const float*)d_in[5];  // [256]
    float* out = (float*)d_out;                  // [64,1024,256]

    const int B = 64;
    // per-batch bytes: xb 0.5MB | gelu 3MB | qkvp(bf16) 3MB | attc(bf16) 2MB
    const size_t WQKVT = 1536 * 256 * 2;             // 786,432
    const size_t WPROT = 1536 * 1536 * 2;            // 4,718,592
    const size_t W4T   = 256 * 1024 * 2;             // 524,288
    const size_t PERB  = 1024 * (256 * 2 + 1536 * 2 + 1536 * 2 + 1024 * 2);
    int CB = 16;                                     // cap: chunk ~L3-resident
    while (CB > 1 && WQKVT + WPROT + W4T + (size_t)CB * PERB > ws_size) CB >>= 1;
    const int NCHUNK = B / CB;
    const int CM = CB * 1024;

    char* w8 = (char*)d_ws;
    unsigned short* wqkvT = (unsigned short*)w8;
    unsigned short* wproT = (unsigned short*)(w8 + WQKVT);
    unsigned short* w4T   = (unsigned short*)(w8 + WQKVT + WPROT);
    char* cbase = w8 + WQKVT + WPROT + W4T;
    unsigned short* xb     = (unsigned short*)cbase;                          // CM*256 bf16
    unsigned short* gelu_b = (unsigned short*)(cbase + (size_t)CM * 512);     // CM*1536 bf16
    unsigned short* qkvp_b = (unsigned short*)(cbase + (size_t)CM * 512 + (size_t)CM * 3072);
    unsigned short* attc   = (unsigned short*)((char*)qkvp_b + (size_t)CM * 3072);

    dim3 blk(256);

    // weight prep (once per launch)
    transpose_bf16<<<dim3(1536 / 32, 256 / 32), blk, 0, stream>>>(w_qkv, wqkvT, 256, 1536);
    transpose_bf16<<<dim3(1536 / 32, 1536 / 32), blk, 0, stream>>>(w_pro, wproT, 1536, 1536);
    make_w4T<<<dim3(256 / 32, 512 / 32), blk, 0, stream>>>(w_out, w4T);

    const int nbx12 = 12;                            // 1536/128
    const int gg    = (CM / 128) * nbx12;            // G1/G2 grid (%8==0)
    const int gg4   = (CM / 128) * 2;                // G4 grid (%8==0)

    for (int c = 0; c < NCHUNK; ++c) {
        const size_t tok0 = (size_t)c * CM;
        conv_bf16<<<512, blk, 0, stream>>>(x + tok0 * 256, xb, CM * 256 / 4);
        gemm_mfma<true, false, true><<<gg, blk, 0, stream>>>(
            xb, wqkvT, nullptr, gelu_b, CM, 1536, 256, nbx12);
        gemm_mfma<false, true, true><<<gg, blk, 0, stream>>>(
            gelu_b, wproT, b_pro, qkvp_b, CM, 1536, 1536, nbx12);
        attn_win<<<dim3(41, 8, CB), blk, 0, stream>>>(qkvp_b, attc);
        gemm_mfma<false, true, false><<<gg4, blk, 0, stream>>>(
            attc, w4T, b_out, out + tok0 * 256, CM, 256, 1024, 2);
    }
}

// Round 6
// 1261.096 us; speedup vs baseline: 1.1874x; 1.0545x over previous
//
#include <hip/hip_runtime.h>
#include <hip/hip_bf16.h>
#include <stdint.h>

// WindowAttention (B=64, N=1024=32x32 tokens, DIM=256, H=8, Dh=64, INNER=512)
// Batch-chunked pipeline (CB batches/chunk from ws_size; cap 64 = single chunk):
//   P0 (once): w_qkv -> [1536][256] bf16^T; w_pro -> [1536][1536] bf16^T;
//              w4T[256][1024] = stack(0.5*w_out^T, 0.5*w_out^T) bf16
//   per chunk:
//     conv: x -> bf16
//     G1 (MFMA): gelu(x @ w_qkv) -> bf16             [CM x 1536]
//     G2 (MFMA): g1 @ w_pro + b_pro -> bf16          [CM x 1536]
//     AT: window attention (fp32 compute, bf16 io) -> attc[CM][1024]
//         (cols 0..511 = stride-0 out, 512..1023 = stride-4 out)
//     G4 (MFMA): attc @ w4T + b_out -> fp32 d_out    (mean folded into w4T)
// R5 -> R6: CB cap 16->64 (fewer launches/gaps, single-dispatch visibility);
// attn softmax wave-parallelized (4 lanes/row + shfl_xor) per m165/m166.

#define BKK 32

typedef short bf16x8 __attribute__((ext_vector_type(8)));
typedef float f32x4 __attribute__((ext_vector_type(4)));

__device__ __forceinline__ unsigned short f2bf(float f) {
    unsigned u = __float_as_uint(f);
    return (unsigned short)((u + 0x7fffu + ((u >> 16) & 1u)) >> 16);
}
__device__ __forceinline__ float bf2f(unsigned short u) {
    return __uint_as_float((unsigned)u << 16);
}
__device__ __forceinline__ float gelu_exact(float v) {
    return 0.5f * v * (1.0f + erff(v * 0.70710678118654752f));
}

// ---------------- fp32 -> bf16 elementwise ----------------
__global__ __launch_bounds__(256) void conv_bf16(const float* __restrict__ src,
                                                 unsigned short* __restrict__ dst, int n4) {
    int i = blockIdx.x * 256 + threadIdx.x;
    const int stride = gridDim.x * 256;
    for (; i < n4; i += stride) {
        float4 v = reinterpret_cast<const float4*>(src)[i];
        ushort4 o;
        o.x = f2bf(v.x); o.y = f2bf(v.y); o.z = f2bf(v.z); o.w = f2bf(v.w);
        reinterpret_cast<ushort4*>(dst)[i] = o;
    }
}

// ---------------- w [K][N] fp32 -> wT [N][K] bf16 ----------------
__global__ __launch_bounds__(256) void transpose_bf16(const float* __restrict__ w,
                                                      unsigned short* __restrict__ wT,
                                                      int K, int N) {
    __shared__ float t[32][33];
    const int kb = blockIdx.y * 32, nb = blockIdx.x * 32;
    const int r = threadIdx.x >> 5, c = threadIdx.x & 31;
    #pragma unroll
    for (int i = 0; i < 4; ++i)
        t[r + i * 8][c] = w[(size_t)(kb + r + i * 8) * N + nb + c];
    __syncthreads();
    #pragma unroll
    for (int i = 0; i < 4; ++i)
        wT[(size_t)(nb + r + i * 8) * K + kb + c] = f2bf(t[c][r + i * 8]);
}

// ---------------- w_out [512][256] -> w4T [256][1024] = [0.5W^T | 0.5W^T] ----------------
__global__ __launch_bounds__(256) void make_w4T(const float* __restrict__ w,
                                                unsigned short* __restrict__ w4T) {
    __shared__ float t[32][33];
    const int kb = blockIdx.y * 32, nb = blockIdx.x * 32;   // k in [0,512), n in [0,256)
    const int r = threadIdx.x >> 5, c = threadIdx.x & 31;
    #pragma unroll
    for (int i = 0; i < 4; ++i)
        t[r + i * 8][c] = w[(size_t)(kb + r + i * 8) * 256 + nb + c];
    __syncthreads();
    #pragma unroll
    for (int i = 0; i < 4; ++i) {
        unsigned short v = f2bf(0.5f * t[c][r + i * 8]);
        size_t n = nb + r + i * 8, k = kb + c;
        w4T[n * 1024 + k]       = v;
        w4T[n * 1024 + 512 + k] = v;
    }
}

// ---------------- MFMA bf16 GEMM: C = A[M][K] @ BT[N][K]^T ----------------
template<bool GELU, bool BIAS, bool OUTBF>
__global__ __launch_bounds__(256) void gemm_mfma(
    const unsigned short* __restrict__ A,   // [M][K] bf16
    const unsigned short* __restrict__ BT,  // [N][K] bf16
    const float* __restrict__ bias,
    void* __restrict__ Cv, int M, int N, int K, int nbx)
{
    __shared__ __align__(16) short lA[128 * BKK];  // [m][k] linear (8 KB)
    __shared__ __align__(16) short lB[128 * BKK];  // [n][k] linear (8 KB)
    const int tid  = threadIdx.x;
    const int lane = tid & 63;
    const int wid  = tid >> 6;

    // XCD-aware swizzle (gridDim.x % 8 == 0): each XCD gets a contiguous chunk.
    const int cpx = gridDim.x >> 3;
    const int wg  = (blockIdx.x & 7) * cpx + (blockIdx.x >> 3);
    const int nb  = wg % nbx, mb = wg / nbx;

    const size_t bm = (size_t)mb * 128;
    const size_t bn = (size_t)nb * 128;

    const int wr = wid >> 1, wc = wid & 1;   // 2x2 wave grid, 64x64 out per wave
    const int mr = wr * 64, nr = wc * 64;

    f32x4 acc[4][4] = {};

    // staging: instr i = wid*2+s covers tile rows [16i,16i+16); lane l ->
    // row 16i + l/4, k-chunk (l&3)*8 shorts. LDS dest = uniform base + lane*16B.
    const int srow = lane >> 2;
    const int sk8  = lane & 3;

    for (int k0 = 0; k0 < K; k0 += BKK) {
        #pragma unroll
        for (int s = 0; s < 2; ++s) {
            const int i = wid * 2 + s;
            const int row = i * 16 + srow;
            const unsigned short* ga = A  + (bm + row) * (size_t)K + k0 + sk8 * 8;
            const unsigned short* gb = BT + (bn + row) * (size_t)K + k0 + sk8 * 8;
            __builtin_amdgcn_global_load_lds(
                (const __attribute__((address_space(1))) unsigned int*)ga,
                (__attribute__((address_space(3))) unsigned int*)(lA + i * 512), 16, 0, 0);
            __builtin_amdgcn_global_load_lds(
                (const __attribute__((address_space(1))) unsigned int*)gb,
                (__attribute__((address_space(3))) unsigned int*)(lB + i * 512), 16, 0, 0);
        }
        __syncthreads();

        const int fr = lane & 15;
        const int fk = (lane >> 4) * 8;
        bf16x8 af[4], bq[4];
        #pragma unroll
        for (int m = 0; m < 4; ++m)
            af[m] = *reinterpret_cast<const bf16x8*>(&lA[(mr + m * 16 + fr) * BKK + fk]);
        #pragma unroll
        for (int n = 0; n < 4; ++n)
            bq[n] = *reinterpret_cast<const bf16x8*>(&lB[(nr + n * 16 + fr) * BKK + fk]);
        #pragma unroll
        for (int m = 0; m < 4; ++m)
            #pragma unroll
            for (int n = 0; n < 4; ++n)
                acc[m][n] = __builtin_amdgcn_mfma_f32_16x16x32_bf16(af[m], bq[n], acc[m][n], 0, 0, 0);
        __syncthreads();
    }

    // epilogue: D frag = col lane&15, row (lane>>4)*4 + j  [verified m89/m91]
    const int fr = lane & 15;
    const int fq = lane >> 4;
    #pragma unroll
    for (int n = 0; n < 4; ++n) {
        const size_t col = bn + nr + n * 16 + fr;
        const float bv = BIAS ? bias[col] : 0.0f;
        #pragma unroll
        for (int m = 0; m < 4; ++m) {
            const size_t rbase = bm + mr + m * 16 + fq * 4;
            f32x4 a = acc[m][n];
            #pragma unroll
            for (int j = 0; j < 4; ++j) {
                float v = a[j] + bv;
                if (GELU) v = gelu_exact(v);
                if (OUTBF)
                    ((unsigned short*)Cv)[(rbase + j) * (size_t)N + col] = f2bf(v);
                else
                    ((float*)Cv)[(rbase + j) * (size_t)N + col] = v;
            }
        }
    }
}

// ---------------- window attention (fp32 compute, bf16 in/out) ----------------
// One block per (window, head, batch-in-chunk). widx 0..15 -> stride 0,
// widx 16..40 -> stride 4 (5x5 grid; edge windows 4 wide).
// Writes bf16 into attc[token][1024]: cols 0..511 = s0, 512..1023 = s4.
__global__ __launch_bounds__(256) void attn_win(
    const unsigned short* __restrict__ qkvp, unsigned short* __restrict__ attc)
{
    __shared__ __align__(16) float qT[64][68];
    __shared__ __align__(16) float kT[64][68];
    __shared__ __align__(16) float vS[64][68];
    __shared__ float pS[64][66];
    __shared__ float invS[64];

    const int widx = blockIdx.x;
    const int h    = blockIdx.y;
    const int b    = blockIdx.z;
    const int tid  = threadIdx.x;

    int r0, c0, nr, nc, sOff;
    if (widx < 16) {
        r0 = (widx >> 2) << 3; c0 = (widx & 3) << 3;
        nr = 8; nc = 8; sOff = 0;
    } else {
        int w  = widx - 16;
        int ri = w / 5, ci = w % 5;
        r0 = (ri == 0) ? 0 : (8 * ri - 4);           // starts {0,4,12,20,28}
        nr = (ri == 0 || ri == 4) ? 4 : 8;
        c0 = (ci == 0) ? 0 : (8 * ci - 4);
        nc = (ci == 0 || ci == 4) ? 4 : 8;
        sOff = 512;
    }
    const int num = nr * nc;                          // 16, 32, or 64
    const int ncl = (nc == 8) ? 3 : 2;
    const size_t tokbase = (size_t)b * 1024;

    for (int f4 = tid; f4 < num * 16; f4 += 256) {
        int t  = f4 >> 4;
        int d4 = (f4 & 15) << 2;
        int n  = ((r0 + (t >> ncl)) << 5) + c0 + (t & (nc - 1));
        const unsigned short* base = qkvp + (tokbase + n) * 1536 + h * 64 + d4;
        ushort4 qv = *reinterpret_cast<const ushort4*>(base);
        ushort4 kv = *reinterpret_cast<const ushort4*>(base + 512);
        ushort4 vv = *reinterpret_cast<const ushort4*>(base + 1024);
        qT[d4 + 0][t] = bf2f(qv.x); qT[d4 + 1][t] = bf2f(qv.y);
        qT[d4 + 2][t] = bf2f(qv.z); qT[d4 + 3][t] = bf2f(qv.w);
        kT[d4 + 0][t] = bf2f(kv.x); kT[d4 + 1][t] = bf2f(kv.y);
        kT[d4 + 2][t] = bf2f(kv.z); kT[d4 + 3][t] = bf2f(kv.w);
        vS[t][d4 + 0] = bf2f(vv.x); vS[t][d4 + 1] = bf2f(vv.y);
        vS[t][d4 + 2] = bf2f(vv.z); vS[t][d4 + 3] = bf2f(vv.w);
    }
    __syncthreads();

    const int i0 = (tid >> 4) << 2;
    const int j0 = (tid & 15) << 2;
    if (i0 < num && j0 < num) {
        float acc[4][4] = {};
        #pragma unroll 16
        for (int d = 0; d < 64; ++d) {
            float4 qv = *reinterpret_cast<const float4*>(&qT[d][i0]);
            float4 kv = *reinterpret_cast<const float4*>(&kT[d][j0]);
            float q_[4] = {qv.x, qv.y, qv.z, qv.w};
            float k_[4] = {kv.x, kv.y, kv.z, kv.w};
            #pragma unroll
            for (int u = 0; u < 4; ++u)
                #pragma unroll
                for (int w = 0; w < 4; ++w)
                    acc[u][w] = fmaf(q_[u], k_[w], acc[u][w]);
        }
        #pragma unroll
        for (int u = 0; u < 4; ++u)
            #pragma unroll
            for (int w = 0; w < 4; ++w)
                pS[i0 + u][j0 + w] = acc[u][w] * 0.125f;
    }
    __syncthreads();

    // padded softmax, wave-parallel: 4 lanes per row (s = tid&3 covers
    // j = s*16..s*16+15), shfl_xor(1,2) reduces within the 4-lane group.
    // Pad keys have logit exactly 0 and ARE included (ref softmaxes over
    // zero-padded keys): max includes 0, denom += (64-num)*exp(-m).
    {
        const int i = tid >> 2, s = tid & 3;
        if (i < num) {
            const int jlo = s * 16;
            const int jhi = (jlo + 16 < num) ? jlo + 16 : num;
            float mp = (num < 64) ? 0.0f : -3.4e38f;
            for (int j = jlo; j < jhi; ++j) mp = fmaxf(mp, pS[i][j]);
            mp = fmaxf(mp, __shfl_xor(mp, 1));
            mp = fmaxf(mp, __shfl_xor(mp, 2));
            float sp = 0.0f;
            for (int j = jlo; j < jhi; ++j) {
                float e = __expf(pS[i][j] - mp);
                pS[i][j] = e;
                sp += e;
            }
            sp += __shfl_xor(sp, 1);
            sp += __shfl_xor(sp, 2);
            if (s == 0)
                invS[i] = 1.0f / (sp + (float)(64 - num) * __expf(-mp));
        }
    }
    __syncthreads();

    const int d0 = j0;
    if (i0 < num) {
        float acc[4][4] = {};
        #pragma unroll 8
        for (int j = 0; j < num; ++j) {
            float4 vv = *reinterpret_cast<const float4*>(&vS[j][d0]);
            float v_[4] = {vv.x, vv.y, vv.z, vv.w};
            float p_[4];
            #pragma unroll
            for (int u = 0; u < 4; ++u) p_[u] = pS[i0 + u][j];
            #pragma unroll
            for (int u = 0; u < 4; ++u)
                #pragma unroll
                for (int w = 0; w < 4; ++w)
                    acc[u][w] = fmaf(p_[u], v_[w], acc[u][w]);
        }
        #pragma unroll
        for (int u = 0; u < 4; ++u) {
            int t = i0 + u;
            int n = ((r0 + (t >> ncl)) << 5) + c0 + (t & (nc - 1));
            float inv = invS[t];
            ushort4 o;
            o.x = f2bf(acc[u][0] * inv); o.y = f2bf(acc[u][1] * inv);
            o.z = f2bf(acc[u][2] * inv); o.w = f2bf(acc[u][3] * inv);
            *reinterpret_cast<ushort4*>(attc + (tokbase + n) * 1024 + sOff + h * 64 + d0) = o;
        }
    }
}

extern "C" void kernel_launch(void* const* d_in, const int* in_sizes, int n_in,
                              void* d_out, int out_size, void* d_ws, size_t ws_size,
                              hipStream_t stream) {
    const float* x     = (const float*)d_in[0];  // [64,1024,256]
    const float* w_qkv = (const float*)d_in[1];  // [256,1536]
    const float* w_pro = (const float*)d_in[2];  // [1536,1536]
    const float* b_pro = (const float*)d_in[3];  // [1536]
    const float* w_out = (const float*)d_in[4];  // [512,256]
    const float* b_out = (const float*)d_in[5];  // [256]
    float* out = (float*)d_out;                  // [64,1024,256]

    const int B = 64;
    // per-batch bytes: xb 0.5MB | gelu 3MB | qkvp(bf16) 3MB | attc(bf16) 2MB
    const size_t WQKVT = 1536 * 256 * 2;             // 786,432
    const size_t WPROT = 1536 * 1536 * 2;            // 4,718,592
    const size_t W4T   = 256 * 1024 * 2;             // 524,288
    const size_t PERB  = 1024 * (256 * 2 + 1536 * 2 + 1536 * 2 + 1024 * 2);
    int CB = 64;                                     // single chunk if ws allows (~556 MB)
    while (CB > 1 && WQKVT + WPROT + W4T + (size_t)CB * PERB > ws_size) CB >>= 1;
    const int NCHUNK = B / CB;
    const int CM = CB * 1024;

    char* w8 = (char*)d_ws;
    unsigned short* wqkvT = (unsigned short*)w8;
    unsigned short* wproT = (unsigned short*)(w8 + WQKVT);
    unsigned short* w4T   = (unsigned short*)(w8 + WQKVT + WPROT);
    char* cbase = w8 + WQKVT + WPROT + W4T;
    unsigned short* xb     = (unsigned short*)cbase;                          // CM*256 bf16
    unsigned short* gelu_b = (unsigned short*)(cbase + (size_t)CM * 512);     // CM*1536 bf16
    unsigned short* qkvp_b = (unsigned short*)(cbase + (size_t)CM * 512 + (size_t)CM * 3072);
    unsigned short* attc   = (unsigned short*)((char*)qkvp_b + (size_t)CM * 3072);

    dim3 blk(256);

    // weight prep (once per launch)
    transpose_bf16<<<dim3(1536 / 32, 256 / 32), blk, 0, stream>>>(w_qkv, wqkvT, 256, 1536);
    transpose_bf16<<<dim3(1536 / 32, 1536 / 32), blk, 0, stream>>>(w_pro, wproT, 1536, 1536);
    make_w4T<<<dim3(256 / 32, 512 / 32), blk, 0, stream>>>(w_out, w4T);

    const int nbx12 = 12;                            // 1536/128
    const int gg    = (CM / 128) * nbx12;            // G1/G2 grid (%8==0)
    const int gg4   = (CM / 128) * 2;                // G4 grid (%8==0)

    for (int c = 0; c < NCHUNK; ++c) {
        const size_t tok0 = (size_t)c * CM;
        conv_bf16<<<2048, blk, 0, stream>>>(x + tok0 * 256, xb, CM * 256 / 4);
        gemm_mfma<true, false, true><<<gg, blk, 0, stream>>>(
            xb, wqkvT, nullptr, gelu_b, CM, 1536, 256, nbx12);
        gemm_mfma<false, true, true><<<gg, blk, 0, stream>>>(
            gelu_b, wproT, b_pro, qkvp_b, CM, 1536, 1536, nbx12);
        attn_win<<<dim3(41, 8, CB), blk, 0, stream>>>(qkvp_b, attc);
        gemm_mfma<false, true, false><<<gg4, blk, 0, stream>>>(
            attc, w4T, b_out, out + tok0 * 256, CM, 256, 1024, 2);
    }
}